// Round 14
// baseline (798.391 us; speedup 1.0000x reference)
//
#include <hip/hip_runtime.h>
#include <hip/hip_bf16.h>
#include <hip/hip_cooperative_groups.h>
#include <math.h>

#define NB    64          // number of segments (B)
#define CD    512         // channels C
#define CV    128         // C / 4 (float4 per row)
#define MIDD  2048        // 4*C
#define NROW  262144      // N
#define EPSV  1e-5f
#define FPT   8           // float4 per thread per chunk
#define FROWS 16          // rows per k_final block (fallback)
#define RS2   32          // fallback: slabs per segment

typedef float fx4 __attribute__((ext_vector_type(4)));

namespace cg = cooperative_groups;

__device__ __forceinline__ float wave_sum64(float x) {
    #pragma unroll
    for (int o = 32; o; o >>= 1) x += __shfl_xor(x, o, 64);
    return x;
}

__device__ __forceinline__ int seg_search(const int* __restrict__ cum, int row) {
    int lo = 0, hi = NB - 1;
    while (lo < hi) {
        int mid = (lo + hi) >> 1;
        if (cum[mid] > row) hi = mid; else lo = mid + 1;
    }
    return lo;
}

// ================= COOPERATIVE FUSED KERNEL, grid-size-agnostic =================
// G blocks x 256 threads, G in {512,1024,2048}. launch_bounds(256,8): VGPR<=64,
// 8 blocks/CU co-residency -> 32 waves/CU at G=2048.
__global__ __launch_bounds__(256, 8) void k_fused(
        const float* __restrict__ x2, const int* __restrict__ npoint,
        const float* __restrict__ W1a, const float* __restrict__ g1a,
        const float* __restrict__ b1a, const float* __restrict__ W2a,
        const float* __restrict__ W1b, const float* __restrict__ g1b,
        const float* __restrict__ b1b, const float* __restrict__ W2b,
        float* __restrict__ P, float* __restrict__ mean_t, float* __restrict__ h_t,
        int* __restrict__ cum, float* __restrict__ out_mean, float* __restrict__ out_w,
        float* __restrict__ out, int slab_shift, int rows_p3) {
    cg::grid_group grid = cg::this_grid();
    __shared__ float smem[2304];

    const int bx = blockIdx.x;
    const int t  = threadIdx.x;
    const int lane = t & 63;
    const int slabs = 1 << slab_shift;

    // ---- Phase 1: partial sums. block (b, rs): slab rs of segment b ----
    {
        int b  = bx >> slab_shift;
        int rs = bx & (slabs - 1);
        int np = npoint[lane];
        int ps = np;
        #pragma unroll
        for (int o = 1; o < 64; o <<= 1) {
            int v = __shfl_up(ps, o, 64);
            if (lane >= o) ps += v;
        }
        int len    = __shfl(np, b, 64);
        int startb = __shfl(ps, b, 64) - len;
        int chunk = (len + slabs - 1) >> slab_shift;
        int r0 = rs * chunk;
        int r1 = min(r0 + chunk, len);

        int c = t & 127;
        int p = t >> 7;
        const fx4* xv = (const fx4*)x2;
        fx4 a0 = 0.f, a1 = 0.f, a2 = 0.f, a3 = 0.f;
        int r = r0 + p;
        for (; r + 6 < r1; r += 8) {
            fx4 v0 = xv[(size_t)(startb + r)     * CV + c];
            fx4 v1 = xv[(size_t)(startb + r + 2) * CV + c];
            fx4 v2 = xv[(size_t)(startb + r + 4) * CV + c];
            fx4 v3 = xv[(size_t)(startb + r + 6) * CV + c];
            a0 += v0; a1 += v1; a2 += v2; a3 += v3;
        }
        for (; r < r1; r += 2)
            a0 += xv[(size_t)(startb + r) * CV + c];

        fx4* red = (fx4*)smem;
        red[t] = (a0 + a1) + (a2 + a3);
        __syncthreads();
        if (t < 128)
            ((fx4*)P)[(size_t)bx * CV + t] = red[t] + red[t + 128];
        __syncthreads();
    }
    grid.sync();

    // ---- Phase 2a: blocks 0..63 reduce slabs -> mean_t (transposed), cum ----
    if (bx < NB) {
        int b = bx;
        int cv = t & 127;
        int h  = t >> 7;             // 0/1: slabs/2 each
        const fx4* Pv = (const fx4*)P;
        fx4 acc = 0.f;
        int half = slabs >> 1;
        for (int rs = h * half; rs < h * half + half; ++rs)
            acc += Pv[((size_t)(b * slabs + rs)) * CV + cv];
        fx4* red = (fx4*)smem;
        red[t] = acc;
        __syncthreads();
        if (t < 128) {
            fx4 s = red[t] + red[t + 128];
            float inv = 1.0f / (float)npoint[b];
            int c = 4 * t;
            mean_t[(size_t)(c + 0) * NB + b] = s.x * inv;
            mean_t[(size_t)(c + 1) * NB + b] = s.y * inv;
            mean_t[(size_t)(c + 2) * NB + b] = s.z * inv;
            mean_t[(size_t)(c + 3) * NB + b] = s.w * inv;
        }
        if (t == 0) {
            int s = 0;
            for (int i = 0; i <= b; ++i) s += npoint[i];
            cum[b] = s;
        }
    }
    grid.sync();

    // ---- Phase 2b: fc1 + BN + ReLU. blocks 0..511: 8 cols each, 4-way K-split ----
    if (bx < 512) {
        int branch = bx >> 8;
        int c0 = (bx & 255) * 8;
        const float* W1 = branch ? W1b : W1a;
        const float* g  = branch ? g1b : g1a;
        const float* bb = branch ? b1b : b1a;
        int w = t >> 6;              // 0..3: K-chunk of 128
        float acc[8];
        #pragma unroll
        for (int i = 0; i < 8; ++i) acc[i] = 0.f;
        int k0 = w * 128;
        for (int k = k0; k < k0 + 128; ++k) {
            float mval = mean_t[(size_t)k * NB + lane];
            const float4* wr = (const float4*)(W1 + (size_t)k * MIDD + c0);
            float4 w0 = wr[0], w1 = wr[1];
            acc[0] += mval * w0.x; acc[1] += mval * w0.y;
            acc[2] += mval * w0.z; acc[3] += mval * w0.w;
            acc[4] += mval * w1.x; acc[5] += mval * w1.y;
            acc[6] += mval * w1.z; acc[7] += mval * w1.w;
        }
        float* red = smem;           // [4][64][9]
        #pragma unroll
        for (int i = 0; i < 8; ++i) red[(w * 64 + lane) * 9 + i] = acc[i];
        __syncthreads();
        #pragma unroll
        for (int pass = 0; pass < 2; ++pass) {
            int col = w + pass * 4;
            float v = red[(0 * 64 + lane) * 9 + col];
            #pragma unroll
            for (int ww = 1; ww < 4; ++ww) v += red[(ww * 64 + lane) * 9 + col];
            float s = wave_sum64(v);
            float m = s * (1.0f / 64.0f);
            float d = v - m;
            float q = wave_sum64(d * d);
            float var = q * (1.0f / 64.0f);
            float val = fmaxf(d * rsqrtf(var + EPSV) * g[c0 + col] + bb[c0 + col], 0.0f);
            h_t[((size_t)branch * MIDD + c0 + col) * NB + lane] = val;
        }
        __syncthreads();
    }
    grid.sync();

    // ---- Phase 2c: fc2. blocks 0..511: 2 cols each, 4-way K-split ----
    if (bx < 512) {
        int branch = bx >> 8;
        int c0 = (bx & 255) * 2;
        const float* W2 = branch ? W2b : W2a;
        int w = t >> 6;              // K-chunk of 512
        float acc0 = 0.f, acc1 = 0.f;
        int k0 = w * 512;
        for (int k = k0; k < k0 + 512; ++k) {
            float hv = h_t[((size_t)branch * MIDD + k) * NB + lane];
            acc0 += hv * W2[(size_t)k * CD + c0];
            acc1 += hv * W2[(size_t)k * CD + c0 + 1];
        }
        float* red = smem;           // [4][64][2]
        red[(w * 64 + lane) * 2 + 0] = acc0;
        red[(w * 64 + lane) * 2 + 1] = acc1;
        __syncthreads();
        if (w < 2) {
            float v = red[(0 * 64 + lane) * 2 + w];
            #pragma unroll
            for (int ww = 1; ww < 4; ++ww) v += red[(ww * 64 + lane) * 2 + w];
            float r = fmaxf(v, 0.0f);
            if (branch)
                out_w[(size_t)lane * CD + c0 + w] = 1.0f / (1.0f + expf(-r));
            else
                out_mean[(size_t)lane * CD + c0 + w] = r;
        }
        __syncthreads();
    }
    grid.sync();

    // ---- Phase 3: final combine. Block re-reads its OWN slab, reverse chunks ----
    {
        int R0 = bx * rows_p3;
        int nchunk = rows_p3 >> 4;   // 16-row chunks
        const fx4* xv = (const fx4*)x2;
        const fx4* wv = (const fx4*)out_w;
        const fx4* mv = (const fx4*)out_mean;
        fx4* ov = (fx4*)out;
        int colv = t & 127;
        for (int j = nchunk - 1; j >= 0; --j) {   // reverse: hottest first
            int base_row = R0 + j * 16;
            size_t base = (size_t)base_row << 7;
            fx4 xs[FPT];
            #pragma unroll
            for (int k = 0; k < FPT; ++k)
                xs[k] = xv[base + ((size_t)k << 8) + t];
            int seg_lo = seg_search(cum, base_row);
            int seg_hi = seg_search(cum, base_row + 15);
            if (seg_lo == seg_hi) {
                fx4 ww = wv[(size_t)seg_lo * CV + colv];
                fx4 mm = mv[(size_t)seg_lo * CV + colv];
                fx4 a = ww * 0.5f + 0.75f;
                #pragma unroll
                for (int k = 0; k < FPT; ++k) {
                    fx4 o = xs[k] * a + mm;
                    __builtin_nontemporal_store(o, &ov[base + ((size_t)k << 8) + t]);
                }
            } else {
                #pragma unroll
                for (int k = 0; k < FPT; ++k) {
                    int row = base_row + ((k * 256 + t) >> 7);
                    int seg = seg_search(cum, row);
                    fx4 ww = wv[(size_t)seg * CV + colv];
                    fx4 mm = mv[(size_t)seg * CV + colv];
                    fx4 o = xs[k] * (ww * 0.5f + 0.75f) + mm;
                    __builtin_nontemporal_store(o, &ov[base + ((size_t)k << 8) + t]);
                }
            }
        }
    }
}

// ================= FALLBACK: R11 5-kernel pipeline (proven 349 µs) =================
__global__ __launch_bounds__(256) void k_partial(const float* __restrict__ x2,
                          const int* __restrict__ npoint,
                          float* __restrict__ P) {
    int bx = blockIdx.x;
    int b  = bx >> 5;
    int rs = bx & (RS2 - 1);
    int t = threadIdx.x;
    int lane = t & 63;
    int np = npoint[lane];
    int ps = np;
    #pragma unroll
    for (int o = 1; o < 64; o <<= 1) {
        int v = __shfl_up(ps, o, 64);
        if (lane >= o) ps += v;
    }
    int len    = __shfl(np, b, 64);
    int startb = __shfl(ps, b, 64) - len;
    int chunk = (len + RS2 - 1) / RS2;
    int r0 = rs * chunk;
    int r1 = min(r0 + chunk, len);
    int c = t & 127;
    int p = t >> 7;
    const fx4* xv = (const fx4*)x2;
    fx4 a0 = 0.f, a1 = 0.f, a2 = 0.f, a3 = 0.f;
    int r = r0 + p;
    for (; r + 6 < r1; r += 8) {
        fx4 v0 = xv[(size_t)(startb + r)     * CV + c];
        fx4 v1 = xv[(size_t)(startb + r + 2) * CV + c];
        fx4 v2 = xv[(size_t)(startb + r + 4) * CV + c];
        fx4 v3 = xv[(size_t)(startb + r + 6) * CV + c];
        a0 += v0; a1 += v1; a2 += v2; a3 += v3;
    }
    for (; r < r1; r += 2)
        a0 += xv[(size_t)(startb + r) * CV + c];
    __shared__ fx4 red[256];
    red[t] = (a0 + a1) + (a2 + a3);
    __syncthreads();
    if (t < 128)
        ((fx4*)P)[(size_t)bx * CV + t] = red[t] + red[t + 128];
}

__global__ __launch_bounds__(512) void k_mean(const float* __restrict__ P,
                       const int* __restrict__ npoint,
                       float* __restrict__ mean_t,
                       int* __restrict__ cum) {
    __shared__ fx4 red[4][CV];
    int b = blockIdx.x;
    int t = threadIdx.x;
    int cv = t & 127;
    int rq = t >> 7;
    const fx4* Pv = (const fx4*)P;
    fx4 acc = 0.f;
    #pragma unroll 8
    for (int rs = rq * 8; rs < rq * 8 + 8; ++rs)
        acc += Pv[((size_t)(b * RS2 + rs)) * CV + cv];
    red[rq][cv] = acc;
    __syncthreads();
    if (t < 128) {
        fx4 s = (red[0][t] + red[1][t]) + (red[2][t] + red[3][t]);
        float inv = 1.0f / (float)npoint[b];
        int c = 4 * t;
        mean_t[(size_t)(c + 0) * NB + b] = s.x * inv;
        mean_t[(size_t)(c + 1) * NB + b] = s.y * inv;
        mean_t[(size_t)(c + 2) * NB + b] = s.z * inv;
        mean_t[(size_t)(c + 3) * NB + b] = s.w * inv;
    }
    if (t == 0) {
        int s = 0;
        for (int i = 0; i <= b; ++i) s += npoint[i];
        cum[b] = s;
    }
}

__global__ __launch_bounds__(512) void k_fc1(const float* __restrict__ mean_t,
                                             const float* __restrict__ W1a,
                                             const float* __restrict__ g1a,
                                             const float* __restrict__ b1a,
                                             const float* __restrict__ W1b,
                                             const float* __restrict__ g1b,
                                             const float* __restrict__ b1b,
                                             const int* __restrict__ cum,
                                             unsigned char* __restrict__ segtab,
                                             float* __restrict__ h_t) {
    __shared__ float red[8][64][9];
    int bx = blockIdx.x;
    int branch = bx >> 8;
    int cg4 = bx & 255;
    int c0 = cg4 * 8;
    const float* W1 = branch ? W1b : W1a;
    const float* g  = branch ? g1b : g1a;
    const float* bb = branch ? b1b : b1a;
    int t = threadIdx.x;
    int gid = bx * 512 + t;
    if (gid < 16384) {
        int r0 = gid * FROWS;
        int lo = seg_search(cum, r0);
        int hi = seg_search(cum, r0 + FROWS - 1);
        segtab[gid] = (lo == hi) ? (unsigned char)lo : (unsigned char)255;
    }
    int lane = t & 63;
    int w = t >> 6;
    float acc[8];
    #pragma unroll
    for (int i = 0; i < 8; ++i) acc[i] = 0.f;
    int k0 = w * 64;
    for (int k = k0; k < k0 + 64; ++k) {
        float mval = mean_t[(size_t)k * NB + lane];
        const float4* wr = (const float4*)(W1 + (size_t)k * MIDD + c0);
        float4 w0 = wr[0], w1 = wr[1];
        acc[0] += mval * w0.x; acc[1] += mval * w0.y;
        acc[2] += mval * w0.z; acc[3] += mval * w0.w;
        acc[4] += mval * w1.x; acc[5] += mval * w1.y;
        acc[6] += mval * w1.z; acc[7] += mval * w1.w;
    }
    #pragma unroll
    for (int i = 0; i < 8; ++i) red[w][lane][i] = acc[i];
    __syncthreads();
    float v = red[0][lane][w];
    #pragma unroll
    for (int ww = 1; ww < 8; ++ww) v += red[ww][lane][w];
    float s = wave_sum64(v);
    float m = s * (1.0f / 64.0f);
    float d = v - m;
    float q = wave_sum64(d * d);
    float var = q * (1.0f / 64.0f);
    float val = fmaxf(d * rsqrtf(var + EPSV) * g[c0 + w] + bb[c0 + w], 0.0f);
    h_t[((size_t)branch * MIDD + c0 + w) * NB + lane] = val;
}

__global__ __launch_bounds__(512) void k_fc2(const float* __restrict__ h_t,
                                             const float* __restrict__ W2a,
                                             const float* __restrict__ W2b,
                                             float* __restrict__ out_mean,
                                             float* __restrict__ out_w) {
    __shared__ float red[8][64][5];
    int bx = blockIdx.x;
    int branch = bx >> 7;
    int cg4 = bx & 127;
    int c0 = cg4 * 4;
    const float* W2 = branch ? W2b : W2a;
    int t = threadIdx.x;
    int lane = t & 63;
    int w = t >> 6;
    float acc[4] = {0.f, 0.f, 0.f, 0.f};
    int k0 = w * 256;
    for (int k = k0; k < k0 + 256; ++k) {
        float hv = h_t[((size_t)branch * MIDD + k) * NB + lane];
        const float4* wr = (const float4*)(W2 + (size_t)k * CD + c0);
        float4 w0 = wr[0];
        acc[0] += hv * w0.x; acc[1] += hv * w0.y;
        acc[2] += hv * w0.z; acc[3] += hv * w0.w;
    }
    #pragma unroll
    for (int i = 0; i < 4; ++i) red[w][lane][i] = acc[i];
    __syncthreads();
    if (w < 4) {
        float v = red[0][lane][w];
        #pragma unroll
        for (int ww = 1; ww < 8; ++ww) v += red[ww][lane][w];
        float r = fmaxf(v, 0.0f);
        if (branch)
            out_w[(size_t)lane * CD + c0 + w] = 1.0f / (1.0f + expf(-r));
        else
            out_mean[(size_t)lane * CD + c0 + w] = r;
    }
}

__global__ __launch_bounds__(256) void k_final(const float* __restrict__ x2,
                        const int* __restrict__ cum,
                        const unsigned char* __restrict__ segtab,
                        const float* __restrict__ out_mean,
                        const float* __restrict__ out_w,
                        float* __restrict__ out) {
    int t = threadIdx.x;
    int bx = (int)gridDim.x - 1 - (int)blockIdx.x;
    size_t base = (size_t)bx << 11;
    int base_row = bx << 4;
    const fx4* xv = (const fx4*)x2;
    const fx4* wv = (const fx4*)out_w;
    const fx4* mv = (const fx4*)out_mean;
    fx4* ov = (fx4*)out;
    int stab = segtab[bx];
    fx4 xs[FPT];
    #pragma unroll
    for (int k = 0; k < FPT; ++k)
        xs[k] = xv[base + ((size_t)k << 8) + t];
    int colv = t & 127;
    if (stab != 255) {
        fx4 ww = wv[(size_t)stab * CV + colv];
        fx4 mm = mv[(size_t)stab * CV + colv];
        fx4 a = ww * 0.5f + 0.75f;
        #pragma unroll
        for (int k = 0; k < FPT; ++k) {
            fx4 o = xs[k] * a + mm;
            __builtin_nontemporal_store(o, &ov[base + ((size_t)k << 8) + t]);
        }
    } else {
        #pragma unroll
        for (int k = 0; k < FPT; ++k) {
            int row = base_row + ((k * 256 + t) >> 7);
            int seg = seg_search(cum, row);
            fx4 ww = wv[(size_t)seg * CV + colv];
            fx4 mm = mv[(size_t)seg * CV + colv];
            fx4 o = xs[k] * (ww * 0.5f + 0.75f) + mm;
            __builtin_nontemporal_store(o, &ov[base + ((size_t)k << 8) + t]);
        }
    }
}

extern "C" void kernel_launch(void* const* d_in, const int* in_sizes, int n_in,
                              void* d_out, int out_size, void* d_ws, size_t ws_size,
                              hipStream_t stream) {
    const float* x2  = (const float*)d_in[0];
    const int*   npt = (const int*)d_in[1];
    const float* W1a = (const float*)d_in[2];
    const float* g1a = (const float*)d_in[3];
    const float* b1a = (const float*)d_in[4];
    const float* W2a = (const float*)d_in[5];
    const float* W1b = (const float*)d_in[6];
    const float* g1b = (const float*)d_in[7];
    const float* b1b = (const float*)d_in[8];
    const float* W2b = (const float*)d_in[9];
    float* out = (float*)d_out;

    const int N   = in_sizes[0] / CD;      // 262144
    const int NC4 = (N * CD) / 4;
    const int NFB = NC4 / (256 * FPT);

    int*   cum      = (int*)d_ws;
    float* out_mean = (float*)d_ws + 64;
    float* out_w    = out_mean + (size_t)NB * CD;
    unsigned char* segtab = (unsigned char*)(out_w + (size_t)NB * CD);

    // --- size the cooperative grid from the runtime's own occupancy math (host-only, deterministic) ---
    int dev = 0;
    hipGetDevice(&dev);
    int numCU = 0;
    hipDeviceGetAttribute(&numCU, hipDeviceAttributeMultiprocessorCount, dev);
    int maxB = 0;
    hipOccupancyMaxActiveBlocksPerMultiprocessor(&maxB, (const void*)k_fused, 256, 0);
    long cap = (long)maxB * (long)numCU;
    int G = (cap >= 2048) ? 2048 : (cap >= 1024) ? 1024 : (cap >= 512) ? 512 : 0;

    hipError_t err = hipErrorUnknown;
    if (G > 0) {
        int slab_shift = __builtin_ctz(G / NB);   // G/NB slabs per segment
        int rows_p3    = N / G;
        float* Pc     = out;                      // [G*CD] scratch, dead before phase 3
        float* mean_c = out + (size_t)G * CD;
        float* h_c    = mean_c + (size_t)NB * CD;
        void* args[] = {
            (void*)&x2, (void*)&npt,
            (void*)&W1a, (void*)&g1a, (void*)&b1a, (void*)&W2a,
            (void*)&W1b, (void*)&g1b, (void*)&b1b, (void*)&W2b,
            (void*)&Pc, (void*)&mean_c, (void*)&h_c,
            (void*)&cum, (void*)&out_mean, (void*)&out_w, (void*)&out,
            (void*)&slab_shift, (void*)&rows_p3
        };
        err = hipLaunchCooperativeKernel((const void*)k_fused, dim3(G), dim3(256),
                                         args, 0, stream);
    }
    if (err != hipSuccess) {
        // deterministic fallback: proven R11 pipeline (~349 µs)
        float* Pf     = out;
        float* mean_f = out + (size_t)NB * RS2 * CD;
        float* h_f    = mean_f + (size_t)NB * CD;
        k_partial<<<NB * RS2, 256, 0, stream>>>(x2, npt, Pf);
        k_mean<<<NB, 512, 0, stream>>>(Pf, npt, mean_f, cum);
        k_fc1<<<2 * (MIDD / 8), 512, 0, stream>>>(mean_f, W1a, g1a, b1a, W1b, g1b, b1b, cum, segtab, h_f);
        k_fc2<<<2 * (CD / 4), 512, 0, stream>>>(h_f, W2a, W2b, out_mean, out_w);
        k_final<<<NFB, 256, 0, stream>>>(x2, cum, segtab, out_mean, out_w, out);
    }
}

// Round 15
// 338.989 us; speedup vs baseline: 2.3552x; 2.3552x over previous
//
#include <hip/hip_runtime.h>
#include <hip/hip_bf16.h>
#include <math.h>

#define NB    64          // number of segments (B)
#define CD    512         // channels C
#define CV    128         // C / 4 (float4 per row)
#define MIDD  2048        // 4*C
#define RS2   32          // slabs per segment in pass 1 (slab = 128 rows = 64KB)
#define EPSV  1e-5f
#define FPT   8           // float4 per thread in k_final
#define FROWS 16          // rows per k_final block

typedef float fx4 __attribute__((ext_vector_type(4)));

__device__ __forceinline__ float wave_sum64(float x) {
    #pragma unroll
    for (int o = 32; o; o >>= 1) x += __shfl_xor(x, o, 64);
    return x;
}

__device__ __forceinline__ int seg_search(const int* __restrict__ cum, int row) {
    int lo = 0, hi = NB - 1;
    while (lo < hi) {
        int mid = (lo + hi) >> 1;
        if (cum[mid] > row) hi = mid; else lo = mid + 1;
    }
    return lo;
}

// ---------------- Pass 1: partial sums with 8-deep load pipeline ----------------
// grid = NB*RS2 = 2048 blocks, 256 threads. Block (b,rs) owns a contiguous 128-row slab.
// Thread t: column c=t&127, half h=t>>7. Per iteration (16 rows): 8 INDEPENDENT loads
// in flight (rows rbase+8h .. rbase+8h+7, same column), then 2x 4-acc add chains.
__global__ __launch_bounds__(256) void k_partial(const float* __restrict__ x2,
                          const int* __restrict__ npoint,
                          float* __restrict__ P) {
    int bx = blockIdx.x;
    int b  = bx >> 5;            // / RS2
    int rs = bx & (RS2 - 1);
    int t = threadIdx.x;
    int lane = t & 63;
    // NB==64: wave-parallel exclusive prefix of npoint
    int np = npoint[lane];
    int ps = np;
    #pragma unroll
    for (int o = 1; o < 64; o <<= 1) {
        int v = __shfl_up(ps, o, 64);
        if (lane >= o) ps += v;
    }
    int len    = __shfl(np, b, 64);
    int startb = __shfl(ps, b, 64) - len;

    int chunk = (len + RS2 - 1) / RS2;      // 128 when len=4096
    int r0 = rs * chunk;
    int r1 = min(r0 + chunk, len);

    int c = t & 127;
    int h = t >> 7;                          // 0 or 1

    fx4 a0 = 0.f, a1 = 0.f, a2 = 0.f, a3 = 0.f;
    const float* px = x2 + (size_t)(startb + r0 + 8 * h) * CD + 4 * c;
    int rbase = r0;
    for (; rbase + 16 <= r1; rbase += 16) {
        fx4 v0 = *(const fx4*)(px + 0 * CD);
        fx4 v1 = *(const fx4*)(px + 1 * CD);
        fx4 v2 = *(const fx4*)(px + 2 * CD);
        fx4 v3 = *(const fx4*)(px + 3 * CD);
        fx4 v4 = *(const fx4*)(px + 4 * CD);
        fx4 v5 = *(const fx4*)(px + 5 * CD);
        fx4 v6 = *(const fx4*)(px + 6 * CD);
        fx4 v7 = *(const fx4*)(px + 7 * CD);
        a0 += v0; a1 += v1; a2 += v2; a3 += v3;
        a0 += v4; a1 += v5; a2 += v6; a3 += v7;
        px += 16 * CD;
    }
    // tail (arbitrary len): rows rbase+8h+i, i<8, if < r1
    #pragma unroll
    for (int i = 0; i < 8; ++i) {
        int rr = rbase + 8 * h + i;
        if (rr < r1)
            a0 += *(const fx4*)(x2 + (size_t)(startb + rr) * CD + 4 * c);
    }

    __shared__ fx4 red[256];
    red[t] = (a0 + a1) + (a2 + a3);
    __syncthreads();
    if (t < 128)
        ((fx4*)P)[(size_t)bx * CV + t] = red[t] + red[t + 128];
}

// ---------------- Pass 1b: reduce 32 slabs -> mean_t (transposed), cum ----------------
__global__ __launch_bounds__(512) void k_mean(const float* __restrict__ P,
                       const int* __restrict__ npoint,
                       float* __restrict__ mean_t,
                       int* __restrict__ cum) {
    __shared__ fx4 red[4][CV];
    int b = blockIdx.x;
    int t = threadIdx.x;
    int cv = t & 127;
    int rq = t >> 7;                 // 0..3
    const fx4* Pv = (const fx4*)P;
    fx4 acc = 0.f;
    #pragma unroll 8
    for (int rs = rq * 8; rs < rq * 8 + 8; ++rs)
        acc += Pv[((size_t)(b * RS2 + rs)) * CV + cv];
    red[rq][cv] = acc;
    __syncthreads();
    if (t < 128) {
        fx4 s = (red[0][t] + red[1][t]) + (red[2][t] + red[3][t]);
        float inv = 1.0f / (float)npoint[b];
        int c = 4 * t;
        mean_t[(size_t)(c + 0) * NB + b] = s.x * inv;
        mean_t[(size_t)(c + 1) * NB + b] = s.y * inv;
        mean_t[(size_t)(c + 2) * NB + b] = s.z * inv;
        mean_t[(size_t)(c + 3) * NB + b] = s.w * inv;
    }
    if (t == 0) {
        int s = 0;
        for (int i = 0; i <= b; ++i) s += npoint[i];
        cum[b] = s;
    }
}

// ---------------- FC1 + BN + ReLU (both branches), 8-way K-split ----------------
__global__ __launch_bounds__(512) void k_fc1(const float* __restrict__ mean_t,
                                             const float* __restrict__ W1a,
                                             const float* __restrict__ g1a,
                                             const float* __restrict__ b1a,
                                             const float* __restrict__ W1b,
                                             const float* __restrict__ g1b,
                                             const float* __restrict__ b1b,
                                             const int* __restrict__ cum,
                                             unsigned char* __restrict__ segtab,
                                             float* __restrict__ h_t) {
    __shared__ float red[8][64][9];
    int bx = blockIdx.x;
    int branch = bx >> 8;
    int cg4 = bx & 255;
    int c0 = cg4 * 8;
    const float* W1 = branch ? W1b : W1a;
    const float* g  = branch ? g1b : g1a;
    const float* bb = branch ? b1b : b1a;
    int t = threadIdx.x;
    int gid = bx * 512 + t;
    if (gid < 16384) {
        int r0 = gid * FROWS;
        int lo = seg_search(cum, r0);
        int hi = seg_search(cum, r0 + FROWS - 1);
        segtab[gid] = (lo == hi) ? (unsigned char)lo : (unsigned char)255;
    }
    int lane = t & 63;
    int w = t >> 6;
    float acc[8];
    #pragma unroll
    for (int i = 0; i < 8; ++i) acc[i] = 0.f;
    int k0 = w * 64;
    for (int k = k0; k < k0 + 64; ++k) {
        float mval = mean_t[(size_t)k * NB + lane];
        const float4* wr = (const float4*)(W1 + (size_t)k * MIDD + c0);
        float4 w0 = wr[0], w1 = wr[1];
        acc[0] += mval * w0.x; acc[1] += mval * w0.y;
        acc[2] += mval * w0.z; acc[3] += mval * w0.w;
        acc[4] += mval * w1.x; acc[5] += mval * w1.y;
        acc[6] += mval * w1.z; acc[7] += mval * w1.w;
    }
    #pragma unroll
    for (int i = 0; i < 8; ++i) red[w][lane][i] = acc[i];
    __syncthreads();
    float v = red[0][lane][w];
    #pragma unroll
    for (int ww = 1; ww < 8; ++ww) v += red[ww][lane][w];
    float s = wave_sum64(v);
    float m = s * (1.0f / 64.0f);
    float d = v - m;
    float q = wave_sum64(d * d);
    float var = q * (1.0f / 64.0f);
    float val = fmaxf(d * rsqrtf(var + EPSV) * g[c0 + w] + bb[c0 + w], 0.0f);
    h_t[((size_t)branch * MIDD + c0 + w) * NB + lane] = val;
}

// ---------------- FC2: 256 blocks (4 cols each) ----------------
__global__ __launch_bounds__(512) void k_fc2(const float* __restrict__ h_t,
                                             const float* __restrict__ W2a,
                                             const float* __restrict__ W2b,
                                             float* __restrict__ out_mean,
                                             float* __restrict__ out_w) {
    __shared__ float red[8][64][5];
    int bx = blockIdx.x;
    int branch = bx >> 7;
    int cg4 = bx & 127;
    int c0 = cg4 * 4;
    const float* W2 = branch ? W2b : W2a;
    int t = threadIdx.x;
    int lane = t & 63;
    int w = t >> 6;
    float acc[4] = {0.f, 0.f, 0.f, 0.f};
    int k0 = w * 256;
    for (int k = k0; k < k0 + 256; ++k) {
        float hv = h_t[((size_t)branch * MIDD + k) * NB + lane];
        const float4* wr = (const float4*)(W2 + (size_t)k * CD + c0);
        float4 w0 = wr[0];
        acc[0] += hv * w0.x; acc[1] += hv * w0.y;
        acc[2] += hv * w0.z; acc[3] += hv * w0.w;
    }
    #pragma unroll
    for (int i = 0; i < 4; ++i) red[w][lane][i] = acc[i];
    __syncthreads();
    if (w < 4) {
        float v = red[0][lane][w];
        #pragma unroll
        for (int ww = 1; ww < 8; ++ww) v += red[ww][lane][w];
        float r = fmaxf(v, 0.0f);
        if (branch)
            out_w[(size_t)lane * CD + c0 + w] = 1.0f / (1.0f + expf(-r));
        else
            out_mean[(size_t)lane * CD + c0 + w] = r;
    }
}

// ---------------- Final combine (R7/R11 best config: 256thr, 8fp4, reversed, nt stores) ----------------
__global__ __launch_bounds__(256) void k_final(const float* __restrict__ x2,
                        const int* __restrict__ cum,
                        const unsigned char* __restrict__ segtab,
                        const float* __restrict__ out_mean,
                        const float* __restrict__ out_w,
                        float* __restrict__ out) {
    int t = threadIdx.x;
    int bx = (int)gridDim.x - 1 - (int)blockIdx.x;
    size_t base = (size_t)bx << 11;
    int base_row = bx << 4;
    const fx4* xv = (const fx4*)x2;
    const fx4* wv = (const fx4*)out_w;
    const fx4* mv = (const fx4*)out_mean;
    fx4* ov = (fx4*)out;
    int stab = segtab[bx];
    fx4 xs[FPT];
    #pragma unroll
    for (int k = 0; k < FPT; ++k)
        xs[k] = xv[base + ((size_t)k << 8) + t];
    int colv = t & 127;
    if (stab != 255) {
        fx4 ww = wv[(size_t)stab * CV + colv];
        fx4 mm = mv[(size_t)stab * CV + colv];
        fx4 a = ww * 0.5f + 0.75f;
        #pragma unroll
        for (int k = 0; k < FPT; ++k) {
            fx4 o = xs[k] * a + mm;
            __builtin_nontemporal_store(o, &ov[base + ((size_t)k << 8) + t]);
        }
    } else {
        #pragma unroll
        for (int k = 0; k < FPT; ++k) {
            int row = base_row + ((k * 256 + t) >> 7);
            int seg = seg_search(cum, row);
            fx4 ww = wv[(size_t)seg * CV + colv];
            fx4 mm = mv[(size_t)seg * CV + colv];
            fx4 o = xs[k] * (0.5f * ww + 0.75f) + mm;
            __builtin_nontemporal_store(o, &ov[base + ((size_t)k << 8) + t]);
        }
    }
}

extern "C" void kernel_launch(void* const* d_in, const int* in_sizes, int n_in,
                              void* d_out, int out_size, void* d_ws, size_t ws_size,
                              hipStream_t stream) {
    const float* x2  = (const float*)d_in[0];
    const int*   npt = (const int*)d_in[1];
    const float* W1a = (const float*)d_in[2];
    const float* g1a = (const float*)d_in[3];
    const float* b1a = (const float*)d_in[4];
    const float* W2a = (const float*)d_in[5];
    const float* W1b = (const float*)d_in[6];
    const float* g1b = (const float*)d_in[7];
    const float* b1b = (const float*)d_in[8];
    const float* W2b = (const float*)d_in[9];
    float* out = (float*)d_out;

    const int N   = in_sizes[0] / CD;      // 262144
    const int NC4 = (N * CD) / 4;
    const int NFB = NC4 / (256 * FPT);     // 16384 k_final blocks

    float* P      = out;                              // [NB*RS2*CD] = 4 MB (dead before k_final)
    float* mean_t = out + (size_t)NB * RS2 * CD;
    float* h_t    = mean_t + (size_t)NB * CD;
    int*   cum      = (int*)d_ws;
    float* out_mean = (float*)d_ws + 64;
    float* out_w    = out_mean + (size_t)NB * CD;
    unsigned char* segtab = (unsigned char*)(out_w + (size_t)NB * CD);

    k_partial<<<NB * RS2, 256, 0, stream>>>(x2, npt, P);
    k_mean<<<NB, 512, 0, stream>>>(P, npt, mean_t, cum);
    k_fc1<<<2 * (MIDD / 8), 512, 0, stream>>>(mean_t, W1a, g1a, b1a, W1b, g1b, b1b, cum, segtab, h_t);
    k_fc2<<<2 * (CD / 4), 512, 0, stream>>>(h_t, W2a, W2b, out_mean, out_w);
    k_final<<<NFB, 256, 0, stream>>>(x2, cum, segtab, out_mean, out_w, out);
}